// Round 14
// baseline (128.305 us; speedup 1.0000x reference)
//
#include <hip/hip_runtime.h>
#include <stdint.h>

#define FP8_MAX 448.0f
#define GBLK 512                 // 2 blocks/CU x 256 CU -> all co-resident
#define KBLK 64                  // blocks 0..63 also do k amax + pack slice
#define CTR_TARGET (GBLK + KBLK) // k-duty blocks increment twice

typedef __attribute__((ext_vector_type(4))) float f32x4;
typedef long long ll;

// flax fp8_ops.compute_scale: sf = fp8_max/amax with fallbacks (qdq multiplier).
__device__ __forceinline__ float scale_factor(float amax, float prev_scale) {
    float sf = FP8_MAX / amax;
    if (!(amax > 0.0f) || !isfinite(amax)) sf = 1.0f / prev_scale;
    return sf;
}

__device__ __forceinline__ unsigned pack4_fp8(float a, float b, float c, float d) {
    int v = __builtin_amdgcn_cvt_pk_fp8_f32(a, b, 0, false);
    v = __builtin_amdgcn_cvt_pk_fp8_f32(c, d, v, true);
    return (unsigned)v;
}

__device__ __forceinline__ float amax4(f32x4 v, float m) {
    float a0 = fmaxf(__builtin_fabsf(v.x), __builtin_fabsf(v.y));
    float a1 = fmaxf(__builtin_fabsf(v.z), __builtin_fabsf(v.w));
    return fmaxf(m, fmaxf(a0, a1));
}

// ---------------------------------------------------------------------------
// Fused single launch (R10 structure; only the BARRIER POLL is changed).
//   phase 0 (bid<KBLK): k amax (redundant, L2-broadcast) + pack 128 words of
//                       the MFMA B-fragment buffer; +1 on ctr.
//   phase 1: stream own 128x256 x-slice (plain loads), local amax ->
//            partials[bid]; +1 on ctr.  (x becomes L3-resident for phase 2 —
//            R10 measured FETCH == one x read total.)
//   barrier: tid0 polls ctr with RELAXED fetch_add(0) + s_sleep backoff.
//            R9/R10 lesson: ACQUIRE-per-poll emits L1/L2 invalidates every
//            iteration -> 512 pollers = invalidate storm = 0.7 TB/s machine.
//            Relaxed RMW reads the coherence point with NO cache ops; one
//            __threadfence() after exit provides the acquire ordering.
//   phase 2: global scales -> depth-2 counted-vmcnt asm pipeline (no reg
//            stash crosses the barrier) -> quant -> swizzled LDS dbuf ->
//            swapped mfma(B,A) = C^T fragments -> dwordx4 stores.
// pack[kstep*1024 + ntile*64 + lane] byte j: col=ntile*16+(lane&15),
//                                            k = kstep*32+(lane>>4)*8+j
// ---------------------------------------------------------------------------
#define ISSUE(RAW, t)                                                          \
    do {                                                                       \
        _Pragma("unroll")                                                      \
        for (int i = 0; i < 8; ++i) {                                          \
            const float* p = xt + (t) * 8192 + i * 1024 + tid * 4;             \
            asm volatile("global_load_dwordx4 %0, %1, off"                     \
                         : "=v"(RAW[i]) : "v"(p) : "memory");                  \
        }                                                                      \
    } while (0)

#define TILE(RAW, b, t)                                                        \
    do {                                                                       \
        _Pragma("unroll")                                                      \
        for (int i = 0; i < 8; ++i) {                                          \
            int row = i * 4 + w;                                               \
            unsigned v = pack4_fp8(RAW[i].x * sf_x, RAW[i].y * sf_x,           \
                                   RAW[i].z * sf_x, RAW[i].w * sf_x);          \
            *(unsigned*)&lds[b][row * 256 + ((lane * 4) ^ ((row & 15) << 3))] = v; \
        }                                                                      \
        asm volatile("s_waitcnt lgkmcnt(0)" ::: "memory");                     \
        __builtin_amdgcn_s_barrier();                                          \
        __builtin_amdgcn_sched_barrier(0);                                     \
        _Pragma("unroll")                                                      \
        for (int rg = 0; rg < 2; ++rg) {                                       \
            unsigned rbase = (unsigned)((rg * 16 + r16) * 256);                \
            ll A[8];                                                           \
            _Pragma("unroll")                                                  \
            for (int ks = 0; ks < 8; ++ks)                                     \
                A[ks] = *(const ll*)&lds[b][rbase +                            \
                        (((unsigned)(kg * 8 + ks * 32)) ^ sw)];                \
            f32x4 acc[4];                                                      \
            _Pragma("unroll")                                                  \
            for (int j = 0; j < 4; ++j) acc[j] = (f32x4){0.f, 0.f, 0.f, 0.f}; \
            _Pragma("unroll")                                                  \
            for (int ks = 0; ks < 8; ++ks)                                     \
                _Pragma("unroll")                                              \
                for (int j = 0; j < 4; ++j)                                    \
                    acc[j] = __builtin_amdgcn_mfma_f32_16x16x32_fp8_fp8(       \
                        Breg[ks * 4 + j], A[ks], acc[j], 0, 0, 0);             \
            _Pragma("unroll")                                                  \
            for (int j = 0; j < 4; ++j) {                                      \
                f32x4 o = acc[j] * outscale;                                   \
                *(f32x4*)&cb[(size_t)((t) * 32 + rg * 16 + r16) * 256 +        \
                             j * 16 + kg * 4] = o;                             \
            }                                                                  \
        }                                                                      \
    } while (0)

__global__ __launch_bounds__(256, 2) void fused_kernel(
    const float* __restrict__ x, const float* __restrict__ kin,
    const float* __restrict__ input_scale, const float* __restrict__ kernel_scale,
    float* __restrict__ C, float* __restrict__ partials,
    float* __restrict__ kamaxf, ll* __restrict__ pack,
    unsigned* __restrict__ ctr) {
    __shared__ float sm[4];
    __shared__ char lds[2][32 * 256];  // dbuf fp8 x-tiles

    int tid = threadIdx.x;
    int lane = tid & 63, w = tid >> 6;
    int kg = lane >> 4, r16 = lane & 15;
    unsigned bid = blockIdx.x;

    // ---- phase 0: k duty (blocks 0..63) ----
    if (bid < KBLK) {
        const f32x4* p = (const f32x4*)kin;
        float m = 0.0f;
        #pragma unroll 8
        for (int t = 0; t < 64; ++t) m = amax4(p[tid + t * 256], m);
        #pragma unroll
        for (int off = 32; off; off >>= 1) m = fmaxf(m, __shfl_down(m, off, 64));
        if (lane == 0) sm[w] = m;
        __syncthreads();
        float am = fmaxf(fmaxf(sm[0], sm[1]), fmaxf(sm[2], sm[3]));
        if (tid == 0) kamaxf[0] = am;  // all KBLK blocks write the same value
        float sf = scale_factor(am, kernel_scale[0]);
        if (tid < 128) {
            int t = (int)bid * 128 + tid;
            int l = t & 63, nt = (t >> 6) & 15, kstep = t >> 10;
            int col = nt * 16 + (l & 15);
            int k0 = kstep * 32 + (l >> 4) * 8;
            float v[8];
            #pragma unroll
            for (int j = 0; j < 8; ++j)
                v[j] = kin[(k0 + j) * 256 + col] * sf;  // |v|<=448(1+eps): RTNE->448
            unsigned lo = pack4_fp8(v[0], v[1], v[2], v[3]);
            unsigned hi = pack4_fp8(v[4], v[5], v[6], v[7]);
            pack[t] = (ll)lo | ((ll)hi << 32);
        }
        __threadfence();
        __syncthreads();
        if (tid == 0)
            __hip_atomic_fetch_add(ctr, 1u, __ATOMIC_RELEASE,
                                   __HIP_MEMORY_SCOPE_AGENT);
        __syncthreads();  // sm[] reused below
    }

    // ---- phase 1: stream own x-slice for local amax (no stash) ----
    const f32x4* xp = (const f32x4*)(x + (size_t)bid * 128 * 256);
    float m = 0.0f;
    #pragma unroll 8
    for (int i = 0; i < 32; ++i) m = amax4(xp[tid + i * 256], m);
    #pragma unroll
    for (int off = 32; off; off >>= 1) m = fmaxf(m, __shfl_down(m, off, 64));
    if (lane == 0) sm[w] = m;
    __syncthreads();
    if (tid == 0) {
        partials[bid] = fmaxf(fmaxf(sm[0], sm[1]), fmaxf(sm[2], sm[3]));
        __threadfence();
        __hip_atomic_fetch_add(ctr, 1u, __ATOMIC_RELEASE,
                               __HIP_MEMORY_SCOPE_AGENT);
    }

    // ---- grid barrier: relaxed-RMW poll (NO per-poll cache invalidates) ----
    if (tid == 0) {
        while (__hip_atomic_fetch_add(ctr, 0u, __ATOMIC_RELAXED,
                                      __HIP_MEMORY_SCOPE_AGENT) < CTR_TARGET)
            __builtin_amdgcn_s_sleep(16);
    }
    __syncthreads();
    __threadfence();  // single acquire-side fence for the whole block

    // ---- phase 2: scales, B fragments, pipelined GEMM ----
    const f32x4* pp = (const f32x4*)partials;
    float mm = 0.0f;
    #pragma unroll
    for (int i = 0; i < 2; ++i) mm = amax4(pp[lane + i * 64], mm);
    #pragma unroll
    for (int off = 32; off; off >>= 1) mm = fmaxf(mm, __shfl_xor(mm, off, 64));
    float sf_x = scale_factor(mm, input_scale[0]);
    float sf_k = scale_factor(kamaxf[0], kernel_scale[0]);
    float outscale = (1.0f / sf_x) * (1.0f / sf_k);

    ll Breg[32];  // [ks*4+j]
    #pragma unroll
    for (int i = 0; i < 32; ++i)
        Breg[i] = pack[(i >> 2) * 1024 + (w * 4 + (i & 3)) * 64 + lane];

    // Drain all compiler-visible memory ops so manual vmcnt counts are exact.
    asm volatile("s_waitcnt vmcnt(0) lgkmcnt(0)" ::: "memory");
    __builtin_amdgcn_sched_barrier(0);

    const float* xt = x + (size_t)bid * 128 * 256;
    float* cb = C + (size_t)bid * 128 * 256 + w * 64;
    unsigned sw = (unsigned)(r16 << 3);

    f32x4 raw0[8], raw1[8], raw2[8];
    ISSUE(raw0, 0);
    ISSUE(raw1, 1);
    ISSUE(raw2, 2);

    // t0: outstanding 24 -> drain raw0 only.
    asm volatile("s_waitcnt vmcnt(16)" ::: "memory");
    __builtin_amdgcn_sched_barrier(0);
    TILE(raw0, 0, 0);   // +8 stores

    // t1: raw1(8), raw2(8), st0(8), raw3(8) -> drain raw1: vmcnt(24).
    ISSUE(raw0, 3);
    asm volatile("s_waitcnt vmcnt(24)" ::: "memory");
    __builtin_amdgcn_sched_barrier(0);
    TILE(raw1, 1, 1);   // +8 stores

    // t2: raw2(8), st0(8), raw3(8), st1(8) -> drain raw2: vmcnt(24).
    asm volatile("s_waitcnt vmcnt(24)" ::: "memory");
    __builtin_amdgcn_sched_barrier(0);
    TILE(raw2, 0, 2);   // +8 stores

    // t3: raw3(8), st1(8), st2(8) -> drain raw3: vmcnt(16).
    asm volatile("s_waitcnt vmcnt(16)" ::: "memory");
    __builtin_amdgcn_sched_barrier(0);
    TILE(raw0, 1, 3);
}

// ---------------------------------------------------------------------------
extern "C" void kernel_launch(void* const* d_in, const int* in_sizes, int n_in,
                              void* d_out, int out_size, void* d_ws, size_t ws_size,
                              hipStream_t stream) {
    const float* x = (const float*)d_in[0];             // [8,8192,256] f32
    const float* k = (const float*)d_in[1];             // [256,256] f32
    const float* input_scale = (const float*)d_in[2];   // [1]
    const float* kernel_scale = (const float*)d_in[3];  // [1]
    float* out = (float*)d_out;

    float* partials = (float*)d_ws;                     // [512]
    float* kamaxf = (float*)((char*)d_ws + 2048);       // [1]
    unsigned* ctr = (unsigned*)((char*)d_ws + 2056);    // [1] spin counter
    ll* pack = (ll*)((char*)d_ws + 16384);              // 64 KiB packed fp8 B

    // ws is NOT re-poisoned between replays: zero the counter every call.
    hipMemsetAsync(ctr, 0, 4, stream);
    fused_kernel<<<GBLK, 256, 0, stream>>>(x, k, input_scale, kernel_scale,
                                           out, partials, kamaxf, pack, ctr);
}